// Round 6
// baseline (287.181 us; speedup 1.0000x reference)
//
#include <hip/hip_runtime.h>
#include <hip/hip_fp16.h>
#include <hip/hip_cooperative_groups.h>

namespace cg = cooperative_groups;

#define NROW 512
#define NCOL 65536

static __device__ __forceinline__ float wave_sum(float x) {
  #pragma unroll
  for (int off = 32; off; off >>= 1) x += __shfl_down(x, off, 64);
  return x;
}

// dot of 8 fp16 (packed in uint4) with 8 fp32 (two float4)
static __device__ __forceinline__ float dot8h(uint4 e, const float4& va, const float4& vb) {
  const __half2* hp = (const __half2*)&e;
  float2 f0 = __half22float2(hp[0]), f1 = __half22float2(hp[1]);
  float2 f2 = __half22float2(hp[2]), f3 = __half22float2(hp[3]);
  return f0.x*va.x + f0.y*va.y + f1.x*va.z + f1.y*va.w
       + f2.x*vb.x + f2.y*vb.y + f3.x*vb.z + f3.y*vb.w;
}

// ---- n1: Eh = (half)exp(-20M); atomic colsum t0 += partials ----------------
// 1024 blocks x 256. Block (band, blk): rows [band*64,+64), cols [blk*512,+512)
__global__ __launch_bounds__(256)
void n1_build(const float* __restrict__ M, __half* __restrict__ Eh,
              float* __restrict__ t0) {
  const int tid = threadIdx.x, bid = blockIdx.x;
  const int band = bid >> 7, blk = bid & 127;
  const int chunk = tid & 127, part = tid >> 7;
  const int col0 = (blk << 9) + (chunk << 2);
  const int r0   = (band << 6) + (part << 5);

  __shared__ float sCol[2 * 512];

  float4 cs = {0.f, 0.f, 0.f, 0.f};
  #pragma unroll 8
  for (int r = r0; r < r0 + 32; ++r) {
    float4 m = *(const float4*)(M + (size_t)r * NCOL + col0);
    __half2 hv[2];
    hv[0] = __floats2half2_rn(__expf(-20.f * m.x), __expf(-20.f * m.y));
    hv[1] = __floats2half2_rn(__expf(-20.f * m.z), __expf(-20.f * m.w));
    *(float2*)(Eh + (size_t)r * NCOL + col0) = *(float2*)hv;
    float2 f0 = __half22float2(hv[0]), f1 = __half22float2(hv[1]);
    cs.x += f0.x; cs.y += f0.y; cs.z += f1.x; cs.w += f1.y;
  }
  *(float4*)(sCol + part * 512 + (chunk << 2)) = cs;
  __syncthreads();
  if (tid < 128) {
    float4 a = *(const float4*)(sCol + (tid << 2));
    float4 b = *(const float4*)(sCol + 512 + (tid << 2));
    float* dst = t0 + (blk << 9) + (tid << 2);
    atomicAdd(dst + 0, a.x + b.x);
    atomicAdd(dst + 1, a.y + b.y);
    atomicAdd(dst + 2, a.z + b.z);
    atomicAdd(dst + 3, a.w + b.w);
  }
}

// ---- n2: rowdot s_i = E v1 (v1 inline from t0) + loss-weight w_i -----------
// 1024 blocks x 256; block = (row, half-row of 32768 cols).
__global__ __launch_bounds__(256)
void n2_rowdot(const __half* __restrict__ Eh, const float* __restrict__ t0,
               float* __restrict__ sPart, float* __restrict__ wPart) {
  const int tid = threadIdx.x, bid = blockIdx.x;
  const int row = bid >> 1, half_ = bid & 1;
  const int cbase = half_ * (NCOL / 2);
  const float am = 1.0f / NROW, bm = 1.0f / NCOL, EPSV = 1e-16f;

  const uint4*  E4 = (const uint4*)(Eh + (size_t)row * NCOL + cbase);
  const float4* T4 = (const float4*)(t0 + cbase);
  __shared__ float sRed[8];

  float s = 0.f, w = 0.f;
  #pragma unroll 4
  for (int it = 0; it < 16; ++it) {
    const int c = (it << 8) + tid;           // uint4 index (8 cols)
    uint4 er = E4[c];
    float4 ta = T4[2*c], tb = T4[2*c + 1];
    float4 va = {bm / (ta.x*am + EPSV), bm / (ta.y*am + EPSV),
                 bm / (ta.z*am + EPSV), bm / (ta.w*am + EPSV)};
    float4 vb = {bm / (tb.x*am + EPSV), bm / (tb.y*am + EPSV),
                 bm / (tb.z*am + EPSV), bm / (tb.w*am + EPSV)};
    const __half2* hp = (const __half2*)&er;
    float2 f0 = __half22float2(hp[0]), f1 = __half22float2(hp[1]);
    float2 f2 = __half22float2(hp[2]), f3 = __half22float2(hp[3]);
    s += f0.x*va.x + f0.y*va.y + f1.x*va.z + f1.y*va.w
       + f2.x*vb.x + f2.y*vb.y + f3.x*vb.z + f3.y*vb.w;
    w += f0.x*va.x*__logf(fmaxf(f0.x, 1e-12f))
       + f0.y*va.y*__logf(fmaxf(f0.y, 1e-12f))
       + f1.x*va.z*__logf(fmaxf(f1.x, 1e-12f))
       + f1.y*va.w*__logf(fmaxf(f1.y, 1e-12f))
       + f2.x*vb.x*__logf(fmaxf(f2.x, 1e-12f))
       + f2.y*vb.y*__logf(fmaxf(f2.y, 1e-12f))
       + f3.x*vb.z*__logf(fmaxf(f3.x, 1e-12f))
       + f3.y*vb.w*__logf(fmaxf(f3.y, 1e-12f));
  }
  s = wave_sum(s); w = wave_sum(w);
  if ((tid & 63) == 0) { sRed[tid >> 6] = s; sRed[4 + (tid >> 6)] = w; }
  __syncthreads();
  if (tid == 0) sPart[bid] = sRed[0] + sRed[1] + sRed[2] + sRed[3];
  if (tid == 1) wPart[bid] = sRed[4] + sRed[5] + sRed[6] + sRed[7];
}

// ---- n3: t2 += partial colsums of E^T u1 (u inline from sPart) -------------
// 1024 blocks x 256, band geometry; band-leader blocks also publish u.
__global__ __launch_bounds__(256)
void n3_colsum2(const __half* __restrict__ Eh, const float* __restrict__ sPart,
                float* __restrict__ u, float* __restrict__ t2) {
  const int tid = threadIdx.x, bid = blockIdx.x;
  const int band = bid >> 7, blk = bid & 127;
  const int chunk = tid & 63, part = tid >> 6;      // 64 chunks x 8 cols; 4 parts x 16 rows
  const int col0 = (blk << 9) + (chunk << 3);
  const float am = 1.0f / NROW, EPSV = 1e-16f;

  __shared__ float sU[64];
  __shared__ float sCol[4 * 512];

  if (tid < 64) {
    const int i = (band << 6) + tid;
    float s = sPart[2*i] + sPart[2*i + 1];
    float uv = am / (s + EPSV);
    sU[tid] = uv;
    if (blk == 0) u[i] = uv;
  }
  __syncthreads();

  float c0=0,c1=0,c2=0,c3=0,c4=0,c5=0,c6=0,c7=0;
  const __half* Eb = Eh + (size_t)(band << 6) * NCOL + col0;
  #pragma unroll 8
  for (int rl = part * 16; rl < part * 16 + 16; ++rl) {
    uint4 er = *(const uint4*)(Eb + (size_t)rl * NCOL);
    const __half2* hp = (const __half2*)&er;
    float2 f0 = __half22float2(hp[0]), f1 = __half22float2(hp[1]);
    float2 f2 = __half22float2(hp[2]), f3 = __half22float2(hp[3]);
    float us = sU[rl];
    c0 = fmaf(f0.x, us, c0); c1 = fmaf(f0.y, us, c1);
    c2 = fmaf(f1.x, us, c2); c3 = fmaf(f1.y, us, c3);
    c4 = fmaf(f2.x, us, c4); c5 = fmaf(f2.y, us, c5);
    c6 = fmaf(f3.x, us, c6); c7 = fmaf(f3.y, us, c7);
  }
  float* sc = sCol + part * 512 + (chunk << 3);
  sc[0]=c0; sc[1]=c1; sc[2]=c2; sc[3]=c3; sc[4]=c4; sc[5]=c5; sc[6]=c6; sc[7]=c7;
  __syncthreads();
  if (tid < 128) {
    const int lc = tid << 2;
    float4 a = *(const float4*)(sCol + lc);
    float4 b = *(const float4*)(sCol + 512 + lc);
    float4 c = *(const float4*)(sCol + 1024 + lc);
    float4 d = *(const float4*)(sCol + 1536 + lc);
    float* dst = t2 + (blk << 9) + lc;
    atomicAdd(dst + 0, a.x + b.x + c.x + d.x);
    atomicAdd(dst + 1, a.y + b.y + c.y + d.y);
    atomicAdd(dst + 2, a.z + b.z + c.z + d.z);
    atomicAdd(dst + 3, a.w + b.w + c.w + d.w);
  }
}

// ---- n4: v = b/(t0/512+eps) stored; err = sum|v*t2 - b| -> eA[0] -----------
__global__ __launch_bounds__(256)
void n4_err(const float* __restrict__ t0, const float* __restrict__ t2,
            float* __restrict__ v, float* __restrict__ eA) {
  const int tid = threadIdx.x;
  const int col0 = (blockIdx.x * 256 + tid) << 2;
  const float am = 1.0f / NROW, bm = 1.0f / NCOL, EPSV = 1e-16f;
  __shared__ float sRed[4];

  float4 t = *(const float4*)(t0 + col0);
  float4 s = *(const float4*)(t2 + col0);
  float4 vv = {bm / (t.x*am + EPSV), bm / (t.y*am + EPSV),
               bm / (t.z*am + EPSV), bm / (t.w*am + EPSV)};
  *(float4*)(v + col0) = vv;
  float pe = fabsf(vv.x*s.x - bm) + fabsf(vv.y*s.y - bm)
           + fabsf(vv.z*s.z - bm) + fabsf(vv.w*s.w - bm);
  pe = wave_sum(pe);
  if ((tid & 63) == 0) sRed[tid >> 6] = pe;
  __syncthreads();
  if (tid == 0) atomicAdd(&eA[0], sRed[0] + sRed[1] + sRed[2] + sRed[3]);
}

// ---- n5: decide; loss = -5 * sum_i u_i * wraw_i ----------------------------
__global__ __launch_bounds__(256)
void n5_decide(const float* __restrict__ eA, const float* __restrict__ u,
               const float* __restrict__ wPart, float* __restrict__ out,
               int* __restrict__ done) {
  const int tid = threadIdx.x;
  __shared__ float sRed[4];
  float l = u[2*tid]     * (wPart[4*tid]     + wPart[4*tid + 1])
          + u[2*tid + 1] * (wPart[4*tid + 2] + wPart[4*tid + 3]);
  l = wave_sum(l);
  if ((tid & 63) == 0) sRed[tid >> 6] = l;
  __syncthreads();
  if (tid == 0) {
    float loss = -5.0f * (sRed[0] + sRed[1] + sRed[2] + sRed[3]);
    if (eA[0] <= 0.005f) { out[0] = loss; done[0] = 1; }
    else                 { out[0] = 0.f;  done[0] = 0; }
  }
}

// ---- n6: cooperative fallback (iters 2..100 + loss), reads Eh --------------
__global__ __launch_bounds__(1024)
void n6_fallback(const __half* __restrict__ Eh, float* __restrict__ out,
                 float* __restrict__ v, float* __restrict__ u,
                 const float* __restrict__ t2, float* __restrict__ eA,
                 const int* __restrict__ done) {
  if (done[0]) return;
  cg::grid_group grid = cg::this_grid();
  const int tid = threadIdx.x, bid = blockIdx.x;
  const float am = 1.0f / NROW, bm = 1.0f / NCOL, EPSV = 1e-16f;

  __shared__ float sU[NROW];
  __shared__ float sCol[32 * 256];   // 32 KB
  __shared__ float sRedA[16], sRedB[16];

  const int chunk = tid & 31, part = tid >> 5;   // 32 chunks x 8 cols; 32 parts x 16 rows
  const int col0 = (bid << 8) + (chunk << 3);
  const int row0 = bid << 1;

  float tt = (tid < 256) ? t2[(bid << 8) + tid] : 0.f;

  int cpt = 1;
  while (true) {
    if (tid < 256) v[(bid << 8) + tid] = bm / (tt + EPSV);
    grid.sync();
    cpt++;

    // rowdot rows row0, row0+1
    {
      const uint4*  E40 = (const uint4*)(Eh + (size_t)row0 * NCOL);
      const uint4*  E41 = (const uint4*)(Eh + (size_t)(row0 + 1) * NCOL);
      const float4* V4  = (const float4*)v;
      float ra = 0.f, rb = 0.f;
      #pragma unroll 4
      for (int it = 0; it < NCOL / 8 / 1024; ++it) {   // 8 iters
        const int c = (it << 10) + tid;
        float4 va = V4[2*c], vb = V4[2*c + 1];
        ra += dot8h(E40[c], va, vb);
        rb += dot8h(E41[c], va, vb);
      }
      ra = wave_sum(ra); rb = wave_sum(rb);
      if ((tid & 63) == 0) { sRedA[tid >> 6] = ra; sRedB[tid >> 6] = rb; }
      __syncthreads();
      if (tid < 2) {
        const float* sr = (tid == 0) ? sRedA : sRedB;
        float s = 0.f;
        #pragma unroll
        for (int w = 0; w < 16; ++w) s += sr[w];
        u[row0 + tid] = am / (s + EPSV);
      }
    }
    grid.sync();
    if (cpt >= 100) break;

    // colsum tt for my 256 cols
    if (tid < NROW) sU[tid] = u[tid];
    __syncthreads();
    float cs[8];
    #pragma unroll
    for (int k = 0; k < 8; ++k) cs[k] = 0.f;
    #pragma unroll 4
    for (int rl = part * 16; rl < part * 16 + 16; ++rl) {
      uint4 er = *(const uint4*)(Eh + (size_t)rl * NCOL + col0);
      const __half2* hp = (const __half2*)&er;
      float2 f0 = __half22float2(hp[0]), f1 = __half22float2(hp[1]);
      float2 f2 = __half22float2(hp[2]), f3 = __half22float2(hp[3]);
      float us = sU[rl];
      cs[0] = fmaf(f0.x, us, cs[0]); cs[1] = fmaf(f0.y, us, cs[1]);
      cs[2] = fmaf(f1.x, us, cs[2]); cs[3] = fmaf(f1.y, us, cs[3]);
      cs[4] = fmaf(f2.x, us, cs[4]); cs[5] = fmaf(f2.y, us, cs[5]);
      cs[6] = fmaf(f3.x, us, cs[6]); cs[7] = fmaf(f3.y, us, cs[7]);
    }
    {
      float* sc = sCol + part * 256 + (chunk << 3);
      #pragma unroll
      for (int k = 0; k < 8; ++k) sc[k] = cs[k];
    }
    __syncthreads();
    if (tid < 256) {
      tt = 0.f;
      #pragma unroll
      for (int p = 0; p < 32; ++p) tt += sCol[p * 256 + tid];
    }

    if (cpt == 51) {
      float pe = (tid < 256) ? fabsf(v[(bid << 8) + tid] * tt - bm) : 0.f;
      pe = wave_sum(pe);
      __syncthreads();
      if ((tid & 63) == 0) sRedA[tid >> 6] = pe;
      __syncthreads();
      if (tid == 0) {
        float s = 0.f;
        #pragma unroll
        for (int w = 0; w < 16; ++w) s += sRedA[w];
        atomicAdd(&eA[1], s);
      }
      grid.sync();
      if (eA[1] <= 0.005f) break;
    }
  }

  // loss = -5 * sum u_i e_ij v_j ln(max(e_ij,1e-12))   (out zeroed by n5)
  __syncthreads();
  if (tid < NROW) sU[tid] = u[tid];
  __syncthreads();
  {
    float4 va = *(const float4*)(v + col0);
    float4 vb = *(const float4*)(v + col0 + 4);
    float lacc = 0.f;
    #pragma unroll 4
    for (int rl = part * 16; rl < part * 16 + 16; ++rl) {
      uint4 er = *(const uint4*)(Eh + (size_t)rl * NCOL + col0);
      const __half2* hp = (const __half2*)&er;
      float2 f0 = __half22float2(hp[0]), f1 = __half22float2(hp[1]);
      float2 f2 = __half22float2(hp[2]), f3 = __half22float2(hp[3]);
      float us = sU[rl];
      lacc += us * (f0.x*va.x*__logf(fmaxf(f0.x, 1e-12f))
                  + f0.y*va.y*__logf(fmaxf(f0.y, 1e-12f))
                  + f1.x*va.z*__logf(fmaxf(f1.x, 1e-12f))
                  + f1.y*va.w*__logf(fmaxf(f1.y, 1e-12f))
                  + f2.x*vb.x*__logf(fmaxf(f2.x, 1e-12f))
                  + f2.y*vb.y*__logf(fmaxf(f2.y, 1e-12f))
                  + f3.x*vb.z*__logf(fmaxf(f3.x, 1e-12f))
                  + f3.y*vb.w*__logf(fmaxf(f3.y, 1e-12f)));
    }
    lacc = wave_sum(lacc);
    if ((tid & 63) == 0) sRedA[tid >> 6] = lacc;
    __syncthreads();
    if (tid == 0) {
      float s = 0.f;
      #pragma unroll
      for (int w = 0; w < 16; ++w) s += sRedA[w];
      atomicAdd(out, -5.0f * s);
    }
  }
}

extern "C" void kernel_launch(void* const* d_in, const int* in_sizes, int n_in,
                              void* d_out, int out_size, void* d_ws, size_t ws_size,
                              hipStream_t stream) {
  const float* M = (const float*)d_in[0];
  float* out = (float*)d_out;

  // ws: Eh | t0 | t2 | eA | done | sPart | wPart | u | v
  const size_t offEh = 0;
  const size_t offT0 = offEh + (size_t)NROW * NCOL * sizeof(__half); // 67 MB
  const size_t offT2 = offT0 + (size_t)NCOL * sizeof(float);
  const size_t offEA = offT2 + (size_t)NCOL * sizeof(float);
  const size_t offDN = offEA + 256;
  const size_t offSP = offDN + 256;
  const size_t offWP = offSP + 4096;
  const size_t offU  = offWP + 4096;
  const size_t offV  = offU  + 2048;
  const size_t need  = offV + (size_t)NCOL * sizeof(float);
  if (ws_size < need) return;

  char* ws = (char*)d_ws;
  __half* Eh   = (__half*)(ws + offEh);
  float* t0    = (float*)(ws + offT0);
  float* t2    = (float*)(ws + offT2);
  float* eA    = (float*)(ws + offEA);
  int*   done  = (int*)(ws + offDN);
  float* sPart = (float*)(ws + offSP);
  float* wPart = (float*)(ws + offWP);
  float* u     = (float*)(ws + offU);
  float* v     = (float*)(ws + offV);

  // zero the atomic accumulators (t0, t2, eA) in one memset
  hipMemsetAsync(ws + offT0, 0, 2 * (size_t)NCOL * sizeof(float) + 256, stream);

  n1_build  <<<dim3(1024), dim3(256), 0, stream>>>(M, Eh, t0);
  n2_rowdot <<<dim3(1024), dim3(256), 0, stream>>>(Eh, t0, sPart, wPart);
  n3_colsum2<<<dim3(1024), dim3(256), 0, stream>>>(Eh, sPart, u, t2);
  n4_err    <<<dim3(64),   dim3(256), 0, stream>>>(t0, t2, v, eA);
  n5_decide <<<dim3(1),    dim3(256), 0, stream>>>(eA, u, wPart, out, done);

  void* args[] = { (void*)&Eh, (void*)&out, (void*)&v, (void*)&u,
                   (void*)&t2, (void*)&eA, (void*)&done };
  hipLaunchCooperativeKernel((void*)n6_fallback, dim3(256), dim3(1024),
                             args, 0, stream);
}

// Round 7
// 274.676 us; speedup vs baseline: 1.0455x; 1.0455x over previous
//
#include <hip/hip_runtime.h>
#include <hip/hip_cooperative_groups.h>

namespace cg = cooperative_groups;

#define NROW 512
#define NCOL 65536
#define BANDS 16           // row bands (32 rows each) for colsum passes

static __device__ __forceinline__ float wave_sum(float x) {
  #pragma unroll
  for (int off = 32; off; off >>= 1) x += __shfl_down(x, off, 64);
  return x;
}

// ---- p1: partial colsums of E = exp(-20M), banded, no atomics --------------
// 2048 blocks x 256. Block (band, blk): rows [band*32,+32), cols [blk*512,+512)
// Thread: 16 rows x one float4 col-chunk; loads batched x4 for MLP.
__global__ __launch_bounds__(256, 8)
void p1_colsum(const float* __restrict__ M, float* __restrict__ t0Part,
               float* __restrict__ eA) {
  const int tid = threadIdx.x, bid = blockIdx.x;
  const int band = bid >> 7, blk = bid & 127;
  const int chunk = tid & 127, part = tid >> 7;
  const int col0 = (blk << 9) + (chunk << 2);
  const int r0   = (band << 5) + (part << 4);

  __shared__ float sCol[2 * 512];
  if (bid == 0 && tid < 3) eA[tid] = 0.f;   // [0]=err1 [1]=err51 [2]=spare

  const float* base = M + (size_t)r0 * NCOL + col0;
  float4 cs = {0.f, 0.f, 0.f, 0.f};
  #pragma unroll
  for (int rb = 0; rb < 16; rb += 4) {
    float4 m0 = *(const float4*)(base + (size_t)(rb + 0) * NCOL);
    float4 m1 = *(const float4*)(base + (size_t)(rb + 1) * NCOL);
    float4 m2 = *(const float4*)(base + (size_t)(rb + 2) * NCOL);
    float4 m3 = *(const float4*)(base + (size_t)(rb + 3) * NCOL);
    cs.x += __expf(-20.f*m0.x) + __expf(-20.f*m1.x) + __expf(-20.f*m2.x) + __expf(-20.f*m3.x);
    cs.y += __expf(-20.f*m0.y) + __expf(-20.f*m1.y) + __expf(-20.f*m2.y) + __expf(-20.f*m3.y);
    cs.z += __expf(-20.f*m0.z) + __expf(-20.f*m1.z) + __expf(-20.f*m2.z) + __expf(-20.f*m3.z);
    cs.w += __expf(-20.f*m0.w) + __expf(-20.f*m1.w) + __expf(-20.f*m2.w) + __expf(-20.f*m3.w);
  }
  *(float4*)(sCol + part * 512 + (chunk << 2)) = cs;
  __syncthreads();
  if (tid < 128) {
    float4 a = *(const float4*)(sCol + (tid << 2));
    float4 b = *(const float4*)(sCol + 512 + (tid << 2));
    float4 t = {a.x + b.x, a.y + b.y, a.z + b.z, a.w + b.w};
    *(float4*)(t0Part + (size_t)band * NCOL + (blk << 9) + (tid << 2)) = t;
  }
}

// ---- p1b: v1 = b / (colsum/512 + eps) --------------------------------------
__global__ __launch_bounds__(256)
void p1b_v1(const float* __restrict__ t0Part, float* __restrict__ v) {
  const int col0 = (blockIdx.x * 256 + threadIdx.x) << 2;
  const float am = 1.0f / NROW, bm = 1.0f / NCOL, EPSV = 1e-16f;
  float4 t = {0.f, 0.f, 0.f, 0.f};
  #pragma unroll
  for (int b = 0; b < BANDS; ++b) {
    float4 p = *(const float4*)(t0Part + (size_t)b * NCOL + col0);
    t.x += p.x; t.y += p.y; t.z += p.z; t.w += p.w;
  }
  float4 vv = {bm / (t.x*am + EPSV), bm / (t.y*am + EPSV),
               bm / (t.z*am + EPSV), bm / (t.w*am + EPSV)};
  *(float4*)(v + col0) = vv;
}

// ---- p2: rowdot s_i = E v1  and loss-weight w_i = sum_j E*M*v1 -------------
// 2048 blocks x 256. Block (row, q): row bid>>2, cols [q*16384,+16384).
__global__ __launch_bounds__(256)
void p2_rowdot(const float* __restrict__ M, const float* __restrict__ v,
               float* __restrict__ sPart, float* __restrict__ wPart) {
  const int tid = threadIdx.x, bid = blockIdx.x;
  const int row = bid >> 2, q = bid & 3;
  const float4* M4 = (const float4*)M + (size_t)row * (NCOL/4) + q * 4096;
  const float4* V4 = (const float4*)v + q * 4096;
  __shared__ float sRed[8];

  float s = 0.f, w = 0.f;
  #pragma unroll
  for (int it = 0; it < 16; it += 4) {
    const int c0 = ((it + 0) << 8) + tid, c1 = ((it + 1) << 8) + tid;
    const int c2 = ((it + 2) << 8) + tid, c3 = ((it + 3) << 8) + tid;
    float4 m0 = M4[c0], m1 = M4[c1], m2 = M4[c2], m3 = M4[c3];
    float4 v0 = V4[c0], v1 = V4[c1], v2 = V4[c2], v3 = V4[c3];
    float4 e0 = {__expf(-20.f*m0.x), __expf(-20.f*m0.y), __expf(-20.f*m0.z), __expf(-20.f*m0.w)};
    float4 e1 = {__expf(-20.f*m1.x), __expf(-20.f*m1.y), __expf(-20.f*m1.z), __expf(-20.f*m1.w)};
    float4 e2 = {__expf(-20.f*m2.x), __expf(-20.f*m2.y), __expf(-20.f*m2.z), __expf(-20.f*m2.w)};
    float4 e3 = {__expf(-20.f*m3.x), __expf(-20.f*m3.y), __expf(-20.f*m3.z), __expf(-20.f*m3.w)};
    s += e0.x*v0.x + e0.y*v0.y + e0.z*v0.z + e0.w*v0.w
       + e1.x*v1.x + e1.y*v1.y + e1.z*v1.z + e1.w*v1.w
       + e2.x*v2.x + e2.y*v2.y + e2.z*v2.z + e2.w*v2.w
       + e3.x*v3.x + e3.y*v3.y + e3.z*v3.z + e3.w*v3.w;
    w += e0.x*m0.x*v0.x + e0.y*m0.y*v0.y + e0.z*m0.z*v0.z + e0.w*m0.w*v0.w
       + e1.x*m1.x*v1.x + e1.y*m1.y*v1.y + e1.z*m1.z*v1.z + e1.w*m1.w*v1.w
       + e2.x*m2.x*v2.x + e2.y*m2.y*v2.y + e2.z*m2.z*v2.z + e2.w*m2.w*v2.w
       + e3.x*m3.x*v3.x + e3.y*m3.y*v3.y + e3.z*m3.z*v3.z + e3.w*m3.w*v3.w;
  }
  s = wave_sum(s); w = wave_sum(w);
  if ((tid & 63) == 0) { sRed[tid >> 6] = s; sRed[4 + (tid >> 6)] = w; }
  __syncthreads();
  if (tid == 0) sPart[bid] = sRed[0] + sRed[1] + sRed[2] + sRed[3];
  if (tid == 1) wPart[bid] = sRed[4] + sRed[5] + sRed[6] + sRed[7];
}

// ---- p3: partial colsums of E^T u1 (u from sPart), banded, no atomics ------
// Same geometry as p1. blk==0 blocks also publish u.
__global__ __launch_bounds__(256, 8)
void p3_colsum2(const float* __restrict__ M, const float* __restrict__ sPart,
                float* __restrict__ u, float* __restrict__ t2Part) {
  const int tid = threadIdx.x, bid = blockIdx.x;
  const int band = bid >> 7, blk = bid & 127;
  const int chunk = tid & 127, part = tid >> 7;
  const int col0 = (blk << 9) + (chunk << 2);
  const int r0l  = part << 4;
  const float am = 1.0f / NROW, EPSV = 1e-16f;

  __shared__ float sU[32];
  __shared__ float sCol[2 * 512];

  if (tid < 32) {
    const int i = (band << 5) + tid;
    float s = sPart[4*i] + sPart[4*i+1] + sPart[4*i+2] + sPart[4*i+3];
    float uv = am / (s + EPSV);
    sU[tid] = uv;
    if (blk == 0) u[i] = uv;
  }
  __syncthreads();

  const float* base = M + (size_t)((band << 5) + r0l) * NCOL + col0;
  float4 cs = {0.f, 0.f, 0.f, 0.f};
  #pragma unroll
  for (int rb = 0; rb < 16; rb += 4) {
    float4 m0 = *(const float4*)(base + (size_t)(rb + 0) * NCOL);
    float4 m1 = *(const float4*)(base + (size_t)(rb + 1) * NCOL);
    float4 m2 = *(const float4*)(base + (size_t)(rb + 2) * NCOL);
    float4 m3 = *(const float4*)(base + (size_t)(rb + 3) * NCOL);
    float u0 = sU[r0l + rb], u1 = sU[r0l + rb + 1];
    float u2 = sU[r0l + rb + 2], u3 = sU[r0l + rb + 3];
    cs.x += __expf(-20.f*m0.x)*u0 + __expf(-20.f*m1.x)*u1 + __expf(-20.f*m2.x)*u2 + __expf(-20.f*m3.x)*u3;
    cs.y += __expf(-20.f*m0.y)*u0 + __expf(-20.f*m1.y)*u1 + __expf(-20.f*m2.y)*u2 + __expf(-20.f*m3.y)*u3;
    cs.z += __expf(-20.f*m0.z)*u0 + __expf(-20.f*m1.z)*u1 + __expf(-20.f*m2.z)*u2 + __expf(-20.f*m3.z)*u3;
    cs.w += __expf(-20.f*m0.w)*u0 + __expf(-20.f*m1.w)*u1 + __expf(-20.f*m2.w)*u2 + __expf(-20.f*m3.w)*u3;
  }
  *(float4*)(sCol + part * 512 + (chunk << 2)) = cs;
  __syncthreads();
  if (tid < 128) {
    float4 a = *(const float4*)(sCol + (tid << 2));
    float4 b = *(const float4*)(sCol + 512 + (tid << 2));
    float4 t = {a.x + b.x, a.y + b.y, a.z + b.z, a.w + b.w};
    *(float4*)(t2Part + (size_t)band * NCOL + (blk << 9) + (tid << 2)) = t;
  }
}

// ---- p4: t2 = reduce(partials) (stored for fallback); err -> eA[0] ---------
__global__ __launch_bounds__(256)
void p4_err(const float* __restrict__ t2Part, const float* __restrict__ v,
            float* __restrict__ t2, float* __restrict__ eA) {
  const int tid = threadIdx.x;
  const int col0 = (blockIdx.x * 256 + tid) << 2;
  const float bm = 1.0f / NCOL;
  __shared__ float sRed[4];

  float4 t = {0.f, 0.f, 0.f, 0.f};
  #pragma unroll
  for (int b = 0; b < BANDS; ++b) {
    float4 p = *(const float4*)(t2Part + (size_t)b * NCOL + col0);
    t.x += p.x; t.y += p.y; t.z += p.z; t.w += p.w;
  }
  *(float4*)(t2 + col0) = t;
  float4 vv = *(const float4*)(v + col0);
  float pe = fabsf(vv.x*t.x - bm) + fabsf(vv.y*t.y - bm)
           + fabsf(vv.z*t.z - bm) + fabsf(vv.w*t.w - bm);
  pe = wave_sum(pe);
  if ((tid & 63) == 0) sRed[tid >> 6] = pe;
  __syncthreads();
  if (tid == 0) atomicAdd(&eA[0], sRed[0] + sRed[1] + sRed[2] + sRed[3]);
}

// ---- p5: decide; loss = 100 * sum_i u_i * w_i ------------------------------
__global__ __launch_bounds__(256)
void p5_decide(const float* __restrict__ eA, const float* __restrict__ u,
               const float* __restrict__ wPart, float* __restrict__ out,
               int* __restrict__ done) {
  const int tid = threadIdx.x;
  __shared__ float sRed[4];
  float l = 0.f;
  #pragma unroll
  for (int k = 0; k < 2; ++k) {
    const int i = 2*tid + k;
    l += u[i] * (wPart[4*i] + wPart[4*i+1] + wPart[4*i+2] + wPart[4*i+3]);
  }
  l = wave_sum(l);
  if ((tid & 63) == 0) sRed[tid >> 6] = l;
  __syncthreads();
  if (tid == 0) {
    float loss = 100.f * (sRed[0] + sRed[1] + sRed[2] + sRed[3]);
    if (eA[0] <= 0.005f) { out[0] = loss; done[0] = 1; }
    else                 { out[0] = 0.f;  done[0] = 0; }
  }
}

// ---- p6: cooperative fallback (iters 2..100 + loss); exits when done -------
__global__ __launch_bounds__(1024)
void p6_fallback(const float* __restrict__ M, float* __restrict__ out,
                 float* __restrict__ v, float* __restrict__ u,
                 const float* __restrict__ tArr, float* __restrict__ eA,
                 const int* __restrict__ done) {
  if (done[0]) return;
  cg::grid_group grid = cg::this_grid();
  const int tid = threadIdx.x, bid = blockIdx.x;
  const float am = 1.0f / NROW, bm = 1.0f / NCOL, EPSV = 1e-16f;

  __shared__ float sU[NROW];
  __shared__ float sCol[16 * 256];
  __shared__ float sRedA[16], sRedB[16];

  const int chunk = tid & 63;
  const int part  = tid >> 6;
  const int col0  = (bid << 8) + (chunk << 2);
  const int r0    = part << 5;
  const int row0  = bid << 1;

  float tt = (tid < 256) ? tArr[(bid << 8) + tid] : 0.f;

  int cpt = 1;
  while (true) {
    if (tid < 256) v[(bid << 8) + tid] = bm / (tt + EPSV);
    grid.sync();
    cpt++;

    {
      const float4* M40 = (const float4*)M + (size_t)row0 * (NCOL / 4);
      const float4* M41 = (const float4*)M + (size_t)(row0 + 1) * (NCOL / 4);
      const float4* V4  = (const float4*)v;
      float ra = 0.f, rb = 0.f;
      #pragma unroll 4
      for (int it = 0; it < NCOL / 4 / 1024; ++it) {
        const int c = (it << 10) + tid;
        float4 vv = V4[c];
        float4 m0 = M40[c], m1 = M41[c];
        ra += __expf(-20.f * m0.x) * vv.x + __expf(-20.f * m0.y) * vv.y
            + __expf(-20.f * m0.z) * vv.z + __expf(-20.f * m0.w) * vv.w;
        rb += __expf(-20.f * m1.x) * vv.x + __expf(-20.f * m1.y) * vv.y
            + __expf(-20.f * m1.z) * vv.z + __expf(-20.f * m1.w) * vv.w;
      }
      ra = wave_sum(ra); rb = wave_sum(rb);
      if ((tid & 63) == 0) { sRedA[tid >> 6] = ra; sRedB[tid >> 6] = rb; }
      __syncthreads();
      if (tid < 2) {
        const float* sr = (tid == 0) ? sRedA : sRedB;
        float s = 0.f;
        #pragma unroll
        for (int w = 0; w < 16; ++w) s += sr[w];
        u[row0 + tid] = am / (s + EPSV);
      }
    }
    grid.sync();
    if (cpt >= 100) break;

    if (tid < NROW) sU[tid] = u[tid];
    __syncthreads();
    float4 cs = {0.f, 0.f, 0.f, 0.f};
    #pragma unroll 4
    for (int r = r0; r < r0 + 32; ++r) {
      float4 m = *(const float4*)(M + (size_t)r * NCOL + col0);
      float us = sU[r];
      cs.x = fmaf(__expf(-20.f * m.x), us, cs.x);
      cs.y = fmaf(__expf(-20.f * m.y), us, cs.y);
      cs.z = fmaf(__expf(-20.f * m.z), us, cs.z);
      cs.w = fmaf(__expf(-20.f * m.w), us, cs.w);
    }
    *(float4*)(sCol + part * 256 + (chunk << 2)) = cs;
    __syncthreads();
    if (tid < 256) {
      tt = 0.f;
      #pragma unroll
      for (int p = 0; p < 16; ++p) tt += sCol[p * 256 + tid];
    }

    if (cpt == 51) {
      float pe = (tid < 256) ? fabsf(v[(bid << 8) + tid] * tt - bm) : 0.f;
      pe = wave_sum(pe);
      __syncthreads();
      if ((tid & 63) == 0) sRedA[tid >> 6] = pe;
      __syncthreads();
      if (tid == 0) {
        float s = 0.f;
        #pragma unroll
        for (int w = 0; w < 16; ++w) s += sRedA[w];
        atomicAdd(&eA[1], s);
      }
      grid.sync();
      if (eA[1] <= 0.005f) break;
    }
  }

  __syncthreads();
  if (tid < NROW) sU[tid] = u[tid];
  __syncthreads();
  {
    const float4 vv = *(const float4*)(v + col0);
    float lacc = 0.f;
    #pragma unroll 4
    for (int r = r0; r < r0 + 32; ++r) {
      float4 m = *(const float4*)(M + (size_t)r * NCOL + col0);
      float us = sU[r];
      lacc += us * (__expf(-20.f * m.x) * m.x * vv.x
                  + __expf(-20.f * m.y) * m.y * vv.y
                  + __expf(-20.f * m.z) * m.z * vv.z
                  + __expf(-20.f * m.w) * m.w * vv.w);
    }
    lacc = wave_sum(lacc);
    if ((tid & 63) == 0) sRedA[tid >> 6] = lacc;
    __syncthreads();
    if (tid == 0) {
      float s = 0.f;
      #pragma unroll
      for (int w = 0; w < 16; ++w) s += sRedA[w];
      atomicAdd(out, 100.f * s);
    }
  }
}

extern "C" void kernel_launch(void* const* d_in, const int* in_sizes, int n_in,
                              void* d_out, int out_size, void* d_ws, size_t ws_size,
                              hipStream_t stream) {
  const float* M = (const float*)d_in[0];
  float* out = (float*)d_out;

  // ws: t0Part(4MB) | t2Part(4MB) | v | t2 | sPart | wPart | u | eA | done
  const size_t off0P = 0;
  const size_t off2P = off0P + (size_t)BANDS * NCOL * sizeof(float);
  const size_t offV  = off2P + (size_t)BANDS * NCOL * sizeof(float);
  const size_t offT2 = offV  + (size_t)NCOL * sizeof(float);
  const size_t offSP = offT2 + (size_t)NCOL * sizeof(float);
  const size_t offWP = offSP + 8192;
  const size_t offU  = offWP + 8192;
  const size_t offEA = offU  + 2048;
  const size_t offDN = offEA + 256;
  const size_t need  = offDN + 256;
  if (ws_size < need) return;

  char* ws = (char*)d_ws;
  float* t0Part = (float*)(ws + off0P);
  float* t2Part = (float*)(ws + off2P);
  float* v      = (float*)(ws + offV);
  float* t2     = (float*)(ws + offT2);
  float* sPart  = (float*)(ws + offSP);
  float* wPart  = (float*)(ws + offWP);
  float* u      = (float*)(ws + offU);
  float* eA     = (float*)(ws + offEA);
  int*   done   = (int*)(ws + offDN);

  p1_colsum <<<dim3(2048), dim3(256), 0, stream>>>(M, t0Part, eA);
  p1b_v1    <<<dim3(64),   dim3(256), 0, stream>>>(t0Part, v);
  p2_rowdot <<<dim3(2048), dim3(256), 0, stream>>>(M, v, sPart, wPart);
  p3_colsum2<<<dim3(2048), dim3(256), 0, stream>>>(M, sPart, u, t2Part);
  p4_err    <<<dim3(64),   dim3(256), 0, stream>>>(t2Part, v, t2, eA);
  p5_decide <<<dim3(1),    dim3(256), 0, stream>>>(eA, u, wPart, out, done);

  void* args[] = { (void*)&M, (void*)&out, (void*)&v, (void*)&u,
                   (void*)&t2, (void*)&eA, (void*)&done };
  hipLaunchCooperativeKernel((void*)p6_fallback, dim3(256), dim3(1024),
                             args, 0, stream);
}